// Round 9
// baseline (183.964 us; speedup 1.0000x reference)
//
#include <hip/hip_runtime.h>
#include <hip/hip_bf16.h>
#include <stdint.h>

// Problem constants
#define M_TOK 2048   // B*S
#define N_OUT 4096   // OUT_F
#define K_IN  4096   // IN_F
#define GROUPSZ 128
#define NGRP  32

typedef signed char i8;
typedef int    intx4  __attribute__((ext_vector_type(4)));
typedef float  floatx4 __attribute__((ext_vector_type(4)));

// ---------------- Kernel 1: fused quantization pass (one dispatch).
// Blocks [0, 2048): quantize one row of x to int8 with per-row scale
//   s_x[n] = rowmax/127 (symmetric). w stays EXACT (ints in [-7,7]).
// Blocks [2048, 2048+4096): narrow w int32 -> int8 (exact), 16 elems/thread.
#define XQ_BLOCKS (M_TOK)                       // 2048, 256 thr = 1 row
#define WQ_BLOCKS (N_OUT * K_IN / 16 / 256)     // 4096

__global__ __launch_bounds__(256) void quant_kernel(
    const float* __restrict__ x, const int* __restrict__ wq,
    i8* __restrict__ xq, i8* __restrict__ wq8, float* __restrict__ sx) {
  __shared__ float red[4];
  int b = blockIdx.x;
  int tid = threadIdx.x;
  if (b < XQ_BLOCKS) {
    const float* xr = x + (size_t)b * K_IN;
    int e0 = tid * 16;
    float4 v0 = *(const float4*)(xr + e0);
    float4 v1 = *(const float4*)(xr + e0 + 4);
    float4 v2 = *(const float4*)(xr + e0 + 8);
    float4 v3 = *(const float4*)(xr + e0 + 12);
    float m = fabsf(v0.x);
    m = fmaxf(m, fabsf(v0.y)); m = fmaxf(m, fabsf(v0.z)); m = fmaxf(m, fabsf(v0.w));
    m = fmaxf(m, fabsf(v1.x)); m = fmaxf(m, fabsf(v1.y)); m = fmaxf(m, fabsf(v1.z)); m = fmaxf(m, fabsf(v1.w));
    m = fmaxf(m, fabsf(v2.x)); m = fmaxf(m, fabsf(v2.y)); m = fmaxf(m, fabsf(v2.z)); m = fmaxf(m, fabsf(v2.w));
    m = fmaxf(m, fabsf(v3.x)); m = fmaxf(m, fabsf(v3.y)); m = fmaxf(m, fabsf(v3.z)); m = fmaxf(m, fabsf(v3.w));
#pragma unroll
    for (int off = 32; off > 0; off >>= 1)
      m = fmaxf(m, __shfl_xor(m, off, 64));
    int lane = tid & 63, wv = tid >> 6;
    if (lane == 0) red[wv] = m;
    __syncthreads();
    m = fmaxf(fmaxf(red[0], red[1]), fmaxf(red[2], red[3]));
    float inv = (m > 0.f) ? 127.f / m : 0.f;
    union { i8 q[16]; int4 v; } u;
    u.q[0]  = (i8)(int)rintf(v0.x * inv); u.q[1]  = (i8)(int)rintf(v0.y * inv);
    u.q[2]  = (i8)(int)rintf(v0.z * inv); u.q[3]  = (i8)(int)rintf(v0.w * inv);
    u.q[4]  = (i8)(int)rintf(v1.x * inv); u.q[5]  = (i8)(int)rintf(v1.y * inv);
    u.q[6]  = (i8)(int)rintf(v1.z * inv); u.q[7]  = (i8)(int)rintf(v1.w * inv);
    u.q[8]  = (i8)(int)rintf(v2.x * inv); u.q[9]  = (i8)(int)rintf(v2.y * inv);
    u.q[10] = (i8)(int)rintf(v2.z * inv); u.q[11] = (i8)(int)rintf(v2.w * inv);
    u.q[12] = (i8)(int)rintf(v3.x * inv); u.q[13] = (i8)(int)rintf(v3.y * inv);
    u.q[14] = (i8)(int)rintf(v3.z * inv); u.q[15] = (i8)(int)rintf(v3.w * inv);
    *(int4*)(xq + (size_t)b * K_IN + e0) = u.v;
    if (tid == 0) sx[b] = m * (1.f / 127.f);
  } else {
    size_t t = (size_t)(b - XQ_BLOCKS) * 256 + tid;   // 1M threads
    size_t base = t * 16;
    const int* src = wq + base;
    int4 a0 = *(const int4*)(src);
    int4 a1 = *(const int4*)(src + 4);
    int4 a2 = *(const int4*)(src + 8);
    int4 a3 = *(const int4*)(src + 12);
    union { i8 q[16]; int4 v; } u;
    u.q[0]  = (i8)a0.x; u.q[1]  = (i8)a0.y; u.q[2]  = (i8)a0.z; u.q[3]  = (i8)a0.w;
    u.q[4]  = (i8)a1.x; u.q[5]  = (i8)a1.y; u.q[6]  = (i8)a1.z; u.q[7]  = (i8)a1.w;
    u.q[8]  = (i8)a2.x; u.q[9]  = (i8)a2.y; u.q[10] = (i8)a2.z; u.q[11] = (i8)a2.w;
    u.q[12] = (i8)a3.x; u.q[13] = (i8)a3.y; u.q[14] = (i8)a3.z; u.q[15] = (i8)a3.w;
    *(int4*)(wq8 + base) = u.v;
  }
}

// ---------------- Kernel 2: int8 GEMM with per-group fp32 rescale + bias.
// y[n,o] = s_x[n] * sum_g( s_w[g,o] * dot_i32(xq[n,g,:], w[o,g,:]) ) + bias[o]
// R9 change: 1024-thread blocks (16 waves, 4x4 wave grid, 32x32 wave-tile,
// 2x2 frags of mfma_i32_16x16x64_i8). Grid stays 512 = 2 blocks/CU, so this
// doubles waves/SIMD 4 -> 8 (max occupancy) — R8 showed both pipes capped at
// ~30% with occupancy the remaining lever. __launch_bounds__(1024, 8) caps
// VGPR at 64 (required for 8 waves/SIMD); per-wave state halved vs R8.
//  - BK=128 == GROUPSZ: K-tile == quant group, int32 MFMA accumulator exact
//    per group; rescale by s_w[g,col] per tile; s_x per row at epilogue.
//  - global_load_lds width=16 staging, XOR-swizzled 16B-chunk layout
//    (R2-verified conflict-free pattern).
#define BM 128
#define BN 128
#define BK 128

__global__ __launch_bounds__(1024, 8) void gemm_i8_kernel(
    const i8* __restrict__ Aq, const i8* __restrict__ Bq,
    const float* __restrict__ sx, const float* __restrict__ sw,
    const float* __restrict__ bias, float* __restrict__ C) {
  __shared__ i8 As[BM * BK];            // 16 KB
  __shared__ i8 Bs[BN * BK];            // 16 KB
  __shared__ float sws[NGRP * BN];      // 16 KB: s_w[g][rowB0 + c]
  __shared__ float sxs[BM];             // 512 B: s_x[rowA0 + r]

  const int tid  = threadIdx.x;
  const int lane = tid & 63;
  const int wave = tid >> 6;       // 0..15
  const int bm = blockIdx.y;
  const int bn = blockIdx.x;
  const int wm = wave >> 2;        // 0..3 -> 32-row slab
  const int wn = wave & 3;         // 0..3 -> 32-col slab

  const int rowA0 = bm * BM;
  const int rowB0 = bn * BN;

  // One-time LDS staging of scales (ordered before use by the loop barriers).
  {
    int g = tid >> 5, c0 = (tid & 31) * 4;    // 1024 thr x float4 = 4096 floats
    *(float4*)(sws + g * BN + c0) =
        *(const float4*)(sw + (size_t)g * N_OUT + rowB0 + c0);
    if (tid < BM) sxs[tid] = sx[rowA0 + tid];
  }

  floatx4 master[2][2];
#pragma unroll
  for (int i = 0; i < 2; ++i)
#pragma unroll
    for (int j = 0; j < 2; ++j) master[i][j] = (floatx4)0.0f;

  const int quad = lane >> 4;      // 0..3
  const int l16  = lane & 15;

  // Staging indices (loop-invariant): 1024 chunks of 16 B per matrix,
  // exactly 1 per thread per matrix.
  const int srow = tid >> 3;                  // tile row 0..127
  const int scol = (((tid & 7) ^ (srow & 7)) << 4);  // swizzled byte offset

  for (int k0 = 0, g = 0; k0 < K_IN; k0 += BK, ++g) {
    __syncthreads();   // previous compute done before LDS overwrite
    {
      const i8* srcA = Aq + (size_t)(rowA0 + srow) * K_IN + k0 + scol;
      const i8* srcB = Bq + (size_t)(rowB0 + srow) * K_IN + k0 + scol;
      __builtin_amdgcn_global_load_lds(
          (const __attribute__((address_space(1))) void*)srcA,
          (__attribute__((address_space(3))) void*)(As + (size_t)(wave * 64) * 16),
          16, 0, 0);
      __builtin_amdgcn_global_load_lds(
          (const __attribute__((address_space(1))) void*)srcB,
          (__attribute__((address_space(3))) void*)(Bs + (size_t)(wave * 64) * 16),
          16, 0, 0);
    }
    __syncthreads();   // vmcnt(0) drain before barrier

    intx4 acci[2][2];
#pragma unroll
    for (int s = 0; s < 2; ++s) {
      const int kc = s * 4 + quad;          // 16B-chunk index 0..7
      intx4 av[2], bv[2];
#pragma unroll
      for (int i = 0; i < 2; ++i) {
        int r = wm * 32 + i * 16 + l16;     // m index
        av[i] = *(const intx4*)(As + (size_t)(r * 8 + (kc ^ (r & 7))) * 16);
      }
#pragma unroll
      for (int j = 0; j < 2; ++j) {
        int r = wn * 32 + j * 16 + l16;     // n index
        bv[j] = *(const intx4*)(Bs + (size_t)(r * 8 + (kc ^ (r & 7))) * 16);
      }
#pragma unroll
      for (int i = 0; i < 2; ++i)
#pragma unroll
        for (int j = 0; j < 2; ++j) {
          intx4 c0 = (s == 0) ? (intx4)0 : acci[i][j];
          acci[i][j] = __builtin_amdgcn_mfma_i32_16x16x64_i8(av[i], bv[j], c0, 0, 0, 0);
        }
    }

    // Per-group rescale: master += f32(acc_i32) * s_w[g, col]
    float swv[2];
#pragma unroll
    for (int j = 0; j < 2; ++j)
      swv[j] = sws[g * BN + wn * 32 + j * 16 + l16];
#pragma unroll
    for (int i = 0; i < 2; ++i)
#pragma unroll
      for (int j = 0; j < 2; ++j)
#pragma unroll
        for (int r = 0; r < 4; ++r)
          master[i][j][r] += (float)acci[i][j][r] * swv[j];
  }

  // Epilogue: C/D layout col = lane&15 (n), row = quad*4 + reg (m).
  // y = master * s_x[row] + bias[col]. Plain stores (R6/R7: ideal WRITE_SIZE).
#pragma unroll
  for (int j = 0; j < 2; ++j) {
    int col = rowB0 + wn * 32 + j * 16 + l16;
    float bv = bias[col];
#pragma unroll
    for (int i = 0; i < 2; ++i) {
      int rloc = wm * 32 + i * 16 + quad * 4;
#pragma unroll
      for (int r = 0; r < 4; ++r) {
        C[(size_t)(rowA0 + rloc + r) * N_OUT + col] =
            master[i][j][r] * sxs[rloc + r] + bv;
      }
    }
  }
}

extern "C" void kernel_launch(void* const* d_in, const int* in_sizes, int n_in,
                              void* d_out, int out_size, void* d_ws, size_t ws_size,
                              hipStream_t stream) {
  const float* x    = (const float*)d_in[0];
  const int*   wq   = (const int*)d_in[1];     // integer input -> int32 per harness
  const float* sw   = (const float*)d_in[2];
  const float* bias = (const float*)d_in[3];
  float* out = (float*)d_out;

  i8*    xq  = (i8*)d_ws;                                          // 8 MB
  i8*    wq8 = (i8*)((char*)d_ws + (size_t)M_TOK * K_IN);          // 16 MB
  float* sx  = (float*)((char*)d_ws + (size_t)M_TOK * K_IN
                                     + (size_t)N_OUT * K_IN);      // 8 KB

  {
    int nblocks = XQ_BLOCKS + WQ_BLOCKS;        // 6144
    quant_kernel<<<nblocks, 256, 0, stream>>>(x, wq, xq, wq8, sx);
  }
  {
    dim3 grid(N_OUT / BN, M_TOK / BM);          // (32, 16) = 512 blocks
    gemm_i8_kernel<<<grid, 1024, 0, stream>>>(xq, wq8, sx, sw, bias, out);
  }
}